// Round 8
// baseline (439.694 us; speedup 1.0000x reference)
//
#include <hip/hip_runtime.h>
#include <stdint.h>

typedef __attribute__((ext_vector_type(8))) short s16x8;
typedef __attribute__((ext_vector_type(4))) float f32x4;

__device__ __forceinline__ short f2bf(float x) {
  uint32_t u = __builtin_bit_cast(uint32_t, x);
  u += 0x7FFFu + ((u >> 16) & 1u);  // RNE
  return (short)(u >> 16);
}

__device__ __forceinline__ void gload16(void* l, const void* g) {
  __builtin_amdgcn_global_load_lds(
      (const __attribute__((address_space(1))) void*)g,
      (__attribute__((address_space(3))) void*)l, 16, 0, 0);
}

__device__ __forceinline__ float gelu_tanh(float x) {
  float u = 0.7978845608028654f * (x + 0.044715f * x * x * x);
  float e = __expf(2.0f * u);
  return x - x / (e + 1.0f);
}

// Aq[m][:] = bf16(codebook[idx[m]][:])
__global__ void gather_cvt(const float* __restrict__ cb, const int* __restrict__ idx,
                           short* __restrict__ out) {
  int m = blockIdx.x * 2 + (threadIdx.x >> 7);
  int c = (threadIdx.x & 127) * 8;
  const float* s = cb + (size_t)idx[m] * 1024 + c;
  s16x8 o;
#pragma unroll
  for (int j = 0; j < 8; ++j) o[j] = f2bf(s[j]);
  *(s16x8*)(out + (size_t)m * 1024 + c) = o;
}

// in [K][N] fp32 -> out [N][K] bf16
__global__ void cvt_T(const float* __restrict__ in, short* __restrict__ out, int K, int N) {
  int Kb = K >> 3;
  int t = blockIdx.x * 256 + threadIdx.x;
  if (t >= N * Kb) return;
  int n = t / Kb;
  int k8 = (t - n * Kb) * 8;
  const float* s = in + (size_t)k8 * N + n;
  s16x8 o;
#pragma unroll
  for (int j = 0; j < 8; ++j) o[j] = f2bf(s[(size_t)j * N]);
  *(s16x8*)(out + (size_t)n * K + k8) = o;
}

// ---------------------------------------------------------------------------
// Triple-buffered + phase-barriered 144x256x64 bf16 GEMM.
// 8 waves 1M x 8N (per-wave 144x32 = 9x2 frags, acc = 72 AGPR).
// LDS ring of 3 tile-buffers (154 KB): tile t reads ring[t%3], stages t+2.
// Only counted wait: vmcnt(7) once per tile (t+1 proven landed; ~2 tiles of
// slack per load). Per tile, TWO barrier-disciplined fat phases (round-2's
// proven interleave): {ds_reads; stage-issue; barrier; lgkmcnt(0);
// setprio(1); 16/20 MFMA; setprio(0); barrier} -- aligns the 2 waves/SIMD so
// MFMA clusters and load-issue overlap across waves (T3/T5 prerequisite).
// Epilogue uses NON-TEMPORAL stores: C streams (h / out) are read-once or
// never re-read; keeping them out of L3 stops eviction of the B-panels
// (round-7 counter: GEMM1 FETCH 281 MB vs 46 MB inputs = write-evict thrash).
// Grids exact multiples of 256 CUs: GEMM1 2048 (8 rounds), GEMM2 512 (2).
// A-tile = 2 full 64-row rounds + 16-row partial (waves 0-1 real, waves 2-7
// -> LDS scratch, keeps per-wave vmcnt uniform; scratch never read).
// MODE 1: bias+GELU -> bf16 nt. MODE 2: bias -> fp32 nt.
// ---------------------------------------------------------------------------
template <int MODE, int K, int N>
__global__ __launch_bounds__(512, 2) void gemm3p(
    const short* __restrict__ A, const short* __restrict__ Bt,
    const float* __restrict__ bias, void* __restrict__ Cv) {
  constexpr int BM = 144, BN = 256;
  constexpr int ATS = BM * 64;          // 9216 shorts (A part of a buffer)
  constexpr int LDSH = (BM + BN) * 64;  // 25600 shorts per ring buffer
  __shared__ short lds[3 * LDSH + 512];  // 3 ring buffers + 1KB scratch = 154624 B

  constexpr int NBN = N / BN;
  const int nwg = gridDim.x;
  int swz = blockIdx.x;
  swz = (swz & 7) * (nwg >> 3) + (swz >> 3);  // XCD swizzle (nwg % 8 == 0)
  const int bm = swz / NBN, bn = swz - (swz / NBN) * NBN;  // row-major (A-panel L2 reuse)

  const int tid = threadIdx.x;
  const int wid = tid >> 6, lane = tid & 63;
  const int lr = lane & 15, hi = lane >> 4;

  // staging: round = 64 rows (8KB); thread -> row (tid>>3), phys slot tid&7,
  // source fetches logical slot (tid&7)^(row&7) (inverse swizzle on source)
  const int sl = (tid & 7) ^ ((tid >> 3) & 7);
  const long rstep = (long)64 * K;
  const short* aptr0 = A + (long)(bm * BM + (tid >> 3)) * K + sl * 8;
  const short* aptrP = A + (long)(bm * BM + 128 + ((tid >> 3) & 15)) * K + sl * 8;
  const short* bptr0 = Bt + (long)(bn * BN + (tid >> 3)) * K + sl * 8;
  const int wlds = wid * 512;            // wave's 1KB block within a round
  const bool realP = (wid < 2);
  constexpr int SCR = 3 * LDSH;          // scratch (partial-round dump, never read)

  // ds_read bases; slot XOR-swizzled by row&7 (= lr&7: frag rows are x16)
  const int aRB = lr * 64;
  const int bRB = ATS + (wid * 32 + lr) * 64;
  const int sk0 = (hi ^ (lr & 7)) * 8;
  const int sk1 = ((4 + hi) ^ (lr & 7)) * 8;

  f32x4 acc[9][2] = {};
  s16x8 af[5][2], bf[2][2];

  constexpr int NT = K >> 6;

  // prologue: tiles 0,1 -> ring0, ring1 (7 loads each: B0-3, A0, A1, Ap)
#pragma unroll
  for (int tt = 0; tt < 2; ++tt) {
    const int wb = tt * LDSH, kk = tt * 64;
#pragma unroll
    for (int r = 0; r < 4; ++r) gload16(&lds[wb + ATS + r * 4096 + wlds], bptr0 + r * rstep + kk);
    gload16(&lds[wb + 0 + wlds], aptr0 + kk);
    gload16(&lds[wb + 4096 + wlds], aptr0 + rstep + kk);
    gload16(realP ? &lds[wb + 8192 + wlds] : &lds[SCR], aptrP + kk);
  }
  asm volatile("s_waitcnt vmcnt(7)" ::: "memory");  // tile0 landed; tile1 in flight
  __builtin_amdgcn_s_barrier();

  int rb0 = 0, rb1 = LDSH, rb2 = 2 * LDSH;  // read | next | write(t+2)

  for (int t = 0; t < NT; ++t) {
    const int kt = ((t + 2 < NT) ? (t + 2) : t) << 6;  // t+2 (wrap: dummy reload)

    // ---- phase 1: m-frags 0-3 x both n-frags; issue t+2 B0-3 ----
#pragma unroll
    for (int mi = 0; mi < 4; ++mi) {
      af[mi][0] = *(const s16x8*)&lds[rb0 + aRB + mi * 1024 + sk0];
      af[mi][1] = *(const s16x8*)&lds[rb0 + aRB + mi * 1024 + sk1];
    }
#pragma unroll
    for (int nj = 0; nj < 2; ++nj) {
      bf[nj][0] = *(const s16x8*)&lds[rb0 + bRB + nj * 1024 + sk0];
      bf[nj][1] = *(const s16x8*)&lds[rb0 + bRB + nj * 1024 + sk1];
    }
#pragma unroll
    for (int r = 0; r < 4; ++r)
      gload16(&lds[rb2 + ATS + r * 4096 + wlds], bptr0 + r * rstep + kt);
    __builtin_amdgcn_s_barrier();  // align waves: loads issued before MFMA
    asm volatile("s_waitcnt lgkmcnt(0)" ::: "memory");
    __builtin_amdgcn_s_setprio(1);
#pragma unroll
    for (int mi = 0; mi < 4; ++mi)
#pragma unroll
      for (int nj = 0; nj < 2; ++nj)
#pragma unroll
        for (int ks = 0; ks < 2; ++ks)
          acc[mi][nj] = __builtin_amdgcn_mfma_f32_16x16x32_bf16(af[mi][ks], bf[nj][ks], acc[mi][nj], 0, 0, 0);
    __builtin_amdgcn_s_setprio(0);
    __builtin_amdgcn_s_barrier();

    // ---- phase 2: m-frags 4-8 x both n-frags; issue t+2 A0,A1,Ap ----
#pragma unroll
    for (int mi = 0; mi < 5; ++mi) {
      af[mi][0] = *(const s16x8*)&lds[rb0 + aRB + (4 + mi) * 1024 + sk0];
      af[mi][1] = *(const s16x8*)&lds[rb0 + aRB + (4 + mi) * 1024 + sk1];
    }
    gload16(&lds[rb2 + 0 + wlds], aptr0 + kt);
    gload16(&lds[rb2 + 4096 + wlds], aptr0 + rstep + kt);
    gload16(realP ? &lds[rb2 + 8192 + wlds] : &lds[SCR], aptrP + kt);
    __builtin_amdgcn_s_barrier();
    asm volatile("s_waitcnt lgkmcnt(0)" ::: "memory");
    __builtin_amdgcn_s_setprio(1);
#pragma unroll
    for (int mi = 0; mi < 5; ++mi)
#pragma unroll
      for (int nj = 0; nj < 2; ++nj)
#pragma unroll
        for (int ks = 0; ks < 2; ++ks)
          acc[4 + mi][nj] = __builtin_amdgcn_mfma_f32_16x16x32_bf16(af[mi][ks], bf[nj][ks], acc[4 + mi][nj], 0, 0, 0);
    __builtin_amdgcn_s_setprio(0);
    // t+1's 7 loads (issued during t-1) proven landed; only this tile's 7 fly.
    asm volatile("s_waitcnt vmcnt(7)" ::: "memory");
    __builtin_amdgcn_s_barrier();
    const int tmp = rb0; rb0 = rb1; rb1 = rb2; rb2 = tmp;
  }

  // epilogue: C/D layout col=lane&15, row=(lane>>4)*4+r; NON-TEMPORAL stores
  const int m0 = bm * BM + hi * 4;
  const int n0 = bn * BN + wid * 32 + lr;
#pragma unroll
  for (int nj = 0; nj < 2; ++nj) {
    const int n = n0 + nj * 16;
    const float bv = bias[n];
#pragma unroll
    for (int mi = 0; mi < 9; ++mi) {
      f32x4 v = acc[mi][nj];
#pragma unroll
      for (int r = 0; r < 4; ++r) {
        const int m = m0 + mi * 16 + r;
        float x = v[r] + bv;
        if (MODE == 1) {
          __builtin_nontemporal_store(f2bf(gelu_tanh(x)), &((short*)Cv)[(size_t)m * N + n]);
        } else {
          __builtin_nontemporal_store(x, &((float*)Cv)[(size_t)m * N + n]);
        }
      }
    }
  }
}

extern "C" void kernel_launch(void* const* d_in, const int* in_sizes, int n_in,
                              void* d_out, int out_size, void* d_ws, size_t ws_size,
                              hipStream_t stream) {
  const int* idx = (const int*)d_in[0];
  const float* cb = (const float*)d_in[1];
  const float* W1 = (const float*)d_in[2];
  const float* b1 = (const float*)d_in[3];
  const float* W2 = (const float*)d_in[4];
  const float* b2 = (const float*)d_in[5];
  float* out = (float*)d_out;

  const int Mtot = 32 * 576;  // 18432 = 128 * 144

  // ws: Aq 40MB | W1T 8MB | W2T 8MB | h chunk
  char* ws = (char*)d_ws;
  short* aq = (short*)(ws);
  short* w1t = (short*)(ws + (size_t)40 * 1024 * 1024);
  short* w2t = (short*)(ws + (size_t)48 * 1024 * 1024);
  short* h = (short*)(ws + (size_t)56 * 1024 * 1024);

  gather_cvt<<<Mtot / 2, 256, 0, stream>>>(cb, idx, aq);
  cvt_T<<<2048, 256, 0, stream>>>(W1, w1t, 1024, 4096);  // -> [4096][1024]
  cvt_T<<<2048, 256, 0, stream>>>(W2, w2t, 4096, 1024);  // -> [1024][4096]

  size_t avail = (ws_size > (size_t)56 * 1024 * 1024) ? ws_size - (size_t)56 * 1024 * 1024 : 0;
  int nc = 1;
  while (nc < 8 && (size_t)(Mtot / nc) * 8192 > avail) nc <<= 1;
  const int Mc = Mtot / nc;  // Mc/144 = 128/nc, integer and %8==0 for nc in {1,2,4,8}

  for (int c = 0; c < nc; ++c) {
    gemm3p<1, 1024, 4096><<<(Mc / 144) * 16, 512, 0, stream>>>(
        aq + (size_t)c * Mc * 1024, w1t, b1, (void*)h);
    gemm3p<2, 4096, 1024><<<(Mc / 144) * 4, 512, 0, stream>>>(
        h, w2t, b2, (void*)(out + (size_t)c * Mc * 1024));
  }
}

// Round 9
// 436.349 us; speedup vs baseline: 1.0077x; 1.0077x over previous
//
#include <hip/hip_runtime.h>
#include <stdint.h>

typedef __attribute__((ext_vector_type(8))) short s16x8;
typedef __attribute__((ext_vector_type(4))) float f32x4;

__device__ __forceinline__ short f2bf(float x) {
  uint32_t u = __builtin_bit_cast(uint32_t, x);
  u += 0x7FFFu + ((u >> 16) & 1u);  // RNE
  return (short)(u >> 16);
}

__device__ __forceinline__ void gload16(void* l, const void* g) {
  __builtin_amdgcn_global_load_lds(
      (const __attribute__((address_space(1))) void*)g,
      (__attribute__((address_space(3))) void*)l, 16, 0, 0);
}

__device__ __forceinline__ float gelu_tanh(float x) {
  float u = 0.7978845608028654f * (x + 0.044715f * x * x * x);
  float e = __expf(2.0f * u);
  return x - x / (e + 1.0f);
}

// Aq[m][:] = bf16(codebook[idx[m]][:])
__global__ void gather_cvt(const float* __restrict__ cb, const int* __restrict__ idx,
                           short* __restrict__ out) {
  int m = blockIdx.x * 2 + (threadIdx.x >> 7);
  int c = (threadIdx.x & 127) * 8;
  const float* s = cb + (size_t)idx[m] * 1024 + c;
  s16x8 o;
#pragma unroll
  for (int j = 0; j < 8; ++j) o[j] = f2bf(s[j]);
  *(s16x8*)(out + (size_t)m * 1024 + c) = o;
}

// in [K][N] fp32 -> out [N][K] bf16
__global__ void cvt_T(const float* __restrict__ in, short* __restrict__ out, int K, int N) {
  int Kb = K >> 3;
  int t = blockIdx.x * 256 + threadIdx.x;
  if (t >= N * Kb) return;
  int n = t / Kb;
  int k8 = (t - n * Kb) * 8;
  const float* s = in + (size_t)k8 * N + n;
  s16x8 o;
#pragma unroll
  for (int j = 0; j < 8; ++j) o[j] = f2bf(s[(size_t)j * N]);
  *(s16x8*)(out + (size_t)n * K + k8) = o;
}

// ---------------------------------------------------------------------------
// 192x256x64 bf16 GEMM, 8 waves 2M x 4N (per-wave 96x64 = 6x4 frags,
// acc = 96 AGPR; LDS reuse ratio 38 vs round-7's 26).
// A double-buffered (issued at tile top -> full-tile slack; L2-warm panels),
// B triple-buffered ring (2-tile lookahead -> covers L3/HBM miss latency).
// Barrier-minimal (round-7 proven): ONE barrier + one counted vmcnt(4) per
// K-tile; in-flight at end of tile t = [B(t+1)x4, A(t+1)x3, B(t+2)x4], so
// vmcnt(4) drains exactly what tile t+1 reads, leaving B(t+2) flying.
// XOR-swizzled LDS (pre-swizzled source + swizzled ds_read, zero conflicts),
// XCD-chunked row-major tile order (A-panel L2 reuse; round-3 lesson).
// Grids: GEMM1 1536 = 6.0 rounds (100%), GEMM2 384 = 1.5 rounds (75%).
// A = 192 rows = 3 exact 64-row staging rounds (no partial-round hack).
// MODE 1: epilogue bias+GELU -> bf16. MODE 2: epilogue bias -> fp32.
// ---------------------------------------------------------------------------
template <int MODE, int K, int N>
__global__ __launch_bounds__(512, 2) void gemmk(
    const short* __restrict__ A, const short* __restrict__ Bt,
    const float* __restrict__ bias, void* __restrict__ Cv) {
  constexpr int BM = 192, BN = 256;
  constexpr int AHS = BM * 64;    // 12288 shorts per A slot
  constexpr int BHS = BN * 64;    // 16384 shorts per B ring buffer
  constexpr int BB = 2 * AHS;     // B ring base (shorts)
  __shared__ short lds[2 * AHS + 3 * BHS];  // 73728 shorts = 147456 B

  constexpr int NBN = N / BN;
  const int nwg = gridDim.x;
  int swz = blockIdx.x;
  swz = (swz & 7) * (nwg >> 3) + (swz >> 3);  // XCD swizzle (nwg % 8 == 0)
  const int bm = swz / NBN, bn = swz - (swz / NBN) * NBN;  // row-major

  const int tid = threadIdx.x;
  const int wid = tid >> 6, lane = tid & 63;
  const int wr = wid >> 2, wc = wid & 3;  // per-wave C: 96 x 64
  const int lr = lane & 15, hi = lane >> 4;

  // staging: round = 64 rows (8KB); thread -> row (tid>>3), phys slot tid&7,
  // source fetches logical slot (tid&7)^(row&7) (inverse swizzle on source)
  const int sl = (tid & 7) ^ ((tid >> 3) & 7);
  const long rstep = (long)64 * K;
  const short* aptr = A + (long)(bm * BM + (tid >> 3)) * K + sl * 8;
  const short* bptr = Bt + (long)(bn * BN + (tid >> 3)) * K + sl * 8;
  const int wlds = wid * 512;  // wave's 1KB block within a staging round

  // ds_read bases; k-slot XOR-swizzled by row&7 (= lr&7: frag rows are x16,
  // wr*96 is a multiple of 8)
  const int aRB = (wr * 96 + lr) * 64;
  const int bRB = (wc * 64 + lr) * 64;
  const int sk0 = (hi ^ (lr & 7)) * 8;
  const int sk1 = ((4 + hi) ^ (lr & 7)) * 8;

  f32x4 acc[6][4] = {};
  s16x8 af[3][2], bf[4][2];

  constexpr int NT = K >> 6;

  // prologue: A(0) -> slot0 (3 rounds), B(0) -> ring0, B(1) -> ring1
#pragma unroll
  for (int r = 0; r < 3; ++r) gload16(&lds[r * 4096 + wlds], aptr + r * rstep);
#pragma unroll
  for (int r = 0; r < 4; ++r) gload16(&lds[BB + r * 4096 + wlds], bptr + r * rstep);
#pragma unroll
  for (int r = 0; r < 4; ++r) gload16(&lds[BB + BHS + r * 4096 + wlds], bptr + r * rstep + 64);
  asm volatile("s_waitcnt vmcnt(4)" ::: "memory");  // A(0),B(0) landed; B(1) flying
  __builtin_amdgcn_s_barrier();

  int rb0 = BB, rb1 = BB + BHS, rb2 = BB + 2 * BHS;  // read | next | write(t+2)

  for (int t = 0; t < NT; ++t) {
    const int ca = (t & 1) * AHS;  // current A slot
    const int na = AHS - ca;       // next A slot (holds retired A(t-1))
    const int ka = ((t + 1 < NT) ? (t + 1) : t) << 6;  // tail: dummy reload, slot unread
    const int kb = ((t + 2 < NT) ? (t + 2) : t) << 6;

    // issue A(t+1) at tile top: full-tile slack, L2-warm panel
#pragma unroll
    for (int r = 0; r < 3; ++r) gload16(&lds[na + r * 4096 + wlds], aptr + r * rstep + ka);

    // ---- half 1: m-frags 0-2 x all 4 n-frags ----
#pragma unroll
    for (int mi = 0; mi < 3; ++mi) {
      af[mi][0] = *(const s16x8*)&lds[ca + aRB + mi * 1024 + sk0];
      af[mi][1] = *(const s16x8*)&lds[ca + aRB + mi * 1024 + sk1];
    }
#pragma unroll
    for (int nj = 0; nj < 4; ++nj) {
      bf[nj][0] = *(const s16x8*)&lds[rb0 + bRB + nj * 1024 + sk0];
      bf[nj][1] = *(const s16x8*)&lds[rb0 + bRB + nj * 1024 + sk1];
    }
    asm volatile("s_waitcnt lgkmcnt(0)" ::: "memory");
    __builtin_amdgcn_s_setprio(1);
#pragma unroll
    for (int mi = 0; mi < 3; ++mi)
#pragma unroll
      for (int nj = 0; nj < 4; ++nj)
#pragma unroll
        for (int ks = 0; ks < 2; ++ks)
          acc[mi][nj] = __builtin_amdgcn_mfma_f32_16x16x32_bf16(af[mi][ks], bf[nj][ks], acc[mi][nj], 0, 0, 0);
    __builtin_amdgcn_s_setprio(0);

    // ---- half 2: m-frags 3-5; issue B(t+2) into ring write slot ----
#pragma unroll
    for (int r = 0; r < 4; ++r)
      gload16(&lds[rb2 + r * 4096 + wlds], bptr + r * rstep + kb);
#pragma unroll
    for (int mi = 0; mi < 3; ++mi) {
      af[mi][0] = *(const s16x8*)&lds[ca + aRB + (3 + mi) * 1024 + sk0];
      af[mi][1] = *(const s16x8*)&lds[ca + aRB + (3 + mi) * 1024 + sk1];
    }
    asm volatile("s_waitcnt lgkmcnt(0)" ::: "memory");
    __builtin_amdgcn_s_setprio(1);
#pragma unroll
    for (int mi = 0; mi < 3; ++mi)
#pragma unroll
      for (int nj = 0; nj < 4; ++nj)
#pragma unroll
        for (int ks = 0; ks < 2; ++ks)
          acc[3 + mi][nj] = __builtin_amdgcn_mfma_f32_16x16x32_bf16(af[mi][ks], bf[nj][ks], acc[3 + mi][nj], 0, 0, 0);
    __builtin_amdgcn_s_setprio(0);

    // queue (old->new): B(t+1)x4, A(t+1)x3, B(t+2)x4 -> keep 4 = B(t+2) only
    asm volatile("s_waitcnt vmcnt(4)" ::: "memory");
    __builtin_amdgcn_s_barrier();
    const int tmp = rb0; rb0 = rb1; rb1 = rb2; rb2 = tmp;
  }

  // epilogue: C/D layout col=lane&15, row=(lane>>4)*4+r
  const int m0 = bm * BM + wr * 96 + hi * 4;
  const int n0 = bn * BN + wc * 64 + lr;
#pragma unroll
  for (int nj = 0; nj < 4; ++nj) {
    const int n = n0 + nj * 16;
    const float bv = bias[n];
#pragma unroll
    for (int mi = 0; mi < 6; ++mi) {
      f32x4 v = acc[mi][nj];
#pragma unroll
      for (int r = 0; r < 4; ++r) {
        const int m = m0 + mi * 16 + r;
        float x = v[r] + bv;
        if (MODE == 1) {
          ((short*)Cv)[(size_t)m * N + n] = f2bf(gelu_tanh(x));
        } else {
          ((float*)Cv)[(size_t)m * N + n] = x;
        }
      }
    }
  }
}

extern "C" void kernel_launch(void* const* d_in, const int* in_sizes, int n_in,
                              void* d_out, int out_size, void* d_ws, size_t ws_size,
                              hipStream_t stream) {
  const int* idx = (const int*)d_in[0];
  const float* cb = (const float*)d_in[1];
  const float* W1 = (const float*)d_in[2];
  const float* b1 = (const float*)d_in[3];
  const float* W2 = (const float*)d_in[4];
  const float* b2 = (const float*)d_in[5];
  float* out = (float*)d_out;

  const int Mtot = 32 * 576;  // 18432 = 96 * 192

  // ws: Aq 40MB | W1T 8MB | W2T 8MB | h chunk
  char* ws = (char*)d_ws;
  short* aq = (short*)(ws);
  short* w1t = (short*)(ws + (size_t)40 * 1024 * 1024);
  short* w2t = (short*)(ws + (size_t)48 * 1024 * 1024);
  short* h = (short*)(ws + (size_t)56 * 1024 * 1024);

  gather_cvt<<<Mtot / 2, 256, 0, stream>>>(cb, idx, aq);
  cvt_T<<<2048, 256, 0, stream>>>(W1, w1t, 1024, 4096);  // -> [4096][1024]
  cvt_T<<<2048, 256, 0, stream>>>(W2, w2t, 4096, 1024);  // -> [1024][4096]

  size_t avail = (ws_size > (size_t)56 * 1024 * 1024) ? ws_size - (size_t)56 * 1024 * 1024 : 0;
  int nc = 1;
  while (nc < 8 && (size_t)(Mtot / nc) * 8192 > avail) nc <<= 1;
  const int Mc = Mtot / nc;  // Mc/192 = 96/nc, integer for nc in {1,2,4,8}

  for (int c = 0; c < nc; ++c) {
    gemmk<1, 1024, 4096><<<(Mc / 192) * 16, 512, 0, stream>>>(
        aq + (size_t)c * Mc * 1024, w1t, b1, (void*)h);
    gemmk<2, 4096, 1024><<<(Mc / 192) * 4, 512, 0, stream>>>(
        h, w2t, b2, (void*)(out + (size_t)c * Mc * 1024));
  }
}